// Round 5
// baseline (1224.992 us; speedup 1.0000x reference)
//
#include <hip/hip_runtime.h>
#include <hip/hip_bf16.h>

// FastKANLayer as one bf16 MFMA GEMM: out[b,j] = A[b,k] @ Wb[k,j], k = i*36+c.
//   c<35: A = cubic B-spline basis (4-tap sparse), Wb = spline_weight[i,j,c]
//   c==35: A = silu(clip(x)),                      Wb = base_scale[i,j]
// M=4096, N=1024, K=36864.
// R10 = R9 (A2 eliminated, A-tile built in-registers per K-step) with the
// correctness fix:
//  - SELECT ORDER: seg0 (tl0) checked BEFORE seg1 (tl1). Proof of safety:
//    seg1 pairs have tl0 = c+1-si0 >= 37-33 = 4 (never match seg0 patterns);
//    the R9 bug was a seg0 pair (c=34,35) with si1==0 matching tl1==-1 and
//    zeroing the c=34 tap (absmax 1.975). Now that path only fires when the
//    lower slot is truly zero, and T1.Dm1|si1=0 == (0,0) is correct.
//  - vmcnt(3) on rotation steps (xN prefetch occupies a FIFO slot), vmcnt(2)
//    otherwise: never stalls on a just-issued load, always drains both
//    prev-step W loads before the barrier.
//  - fallback launcher passes sw again (R9 passed nullptr).
// Carried: R5 triple-buffer structure, R6-proven baked chunk-XOR swizzle
// (conflicts = 0), R8 prep_w2, NSPLIT=4 atomics.

#define IN_DIM 1024
#define OUT_DIM 1024
#define NC 35
#define KPI 36
#define KTOT (IN_DIM * KPI)      // 36864
#define NW (KTOT / 32)           // 1152 k-windows of 32
#define MROWS 4096
#define BM 256
#define BN 256
#define BK 32
#define NSPLIT 4
#define WPC (NW / NSPLIT)        // 288 windows per kc chunk

typedef __attribute__((ext_vector_type(8))) __bf16 bf16x8;
typedef __attribute__((ext_vector_type(4))) float f32x4;

__device__ __forceinline__ unsigned short f2bf(float f) {
  unsigned int u = __builtin_bit_cast(unsigned int, f);
  u = (u + 0x7FFFu + ((u >> 16) & 1u)) >> 16;   // RNE
  return (unsigned short)u;
}

__device__ __forceinline__ uint4 pack8(const unsigned short* v) {
  uint4 t4;
  t4.x = (unsigned)v[0] | ((unsigned)v[1] << 16);
  t4.y = (unsigned)v[2] | ((unsigned)v[3] << 16);
  t4.z = (unsigned)v[4] | ((unsigned)v[5] << 16);
  t4.w = (unsigned)v[6] | ((unsigned)v[7] << 16);
  return t4;
}

// ---- prep: W2[w][n][32] bf16 (75.5 MB), swizzled LDS tile image. ----
// (R8-proven, unchanged.)
__global__ __launch_bounds__(256) void prep_w2(const float* __restrict__ sw,
                                               const float* __restrict__ bs,
                                               unsigned short* __restrict__ w2) {
  const int tid = threadIdx.x;
  const int w = blockIdx.x;
  const int n = blockIdx.y * 256 + tid;
  const int k0 = w * 32;
  const int i0 = k0 / KPI;
  const int off0 = k0 - i0 * KPI;                 // in {0,4,...,32}
  const int split = (KPI - off0 < 32) ? (KPI - off0) : 32;
  const int i1 = (i0 + 1 < IN_DIM) ? (i0 + 1) : i0;   // clamp (unused if split==32)
  const float* p0 = sw + ((size_t)i0 * OUT_DIM + n) * NC;
  const float* p1 = sw + ((size_t)i1 * OUT_DIM + n) * NC;
  const float bsv = bs[(size_t)i0 * OUT_DIM + n];
  const int swz = (tid >> 1) & 3;                 // row bits 1:2 -> chunk XOR

  unsigned short v[32];
#pragma unroll
  for (int kk = 0; kk < 32; ++kk) {
    const int c = off0 + kk;                      // wave-uniform
    const bool ph0 = (kk < split);
    const float* base = ph0 ? p0 : p1;
    const int idx = ph0 ? (c < NC ? c : 0) : (kk - split);  // clamped: no OOB
    float fv = base[idx];
    if (ph0 && c == NC) fv = bsv;                 // silu-weight slot
    v[kk] = f2bf(fv);
  }
  uint4* dst = (uint4*)(w2 + ((size_t)w * OUT_DIM + n) * 32);
#pragma unroll
  for (int j = 0; j < 4; ++j) dst[j ^ swz] = pack8(&v[8 * j]);
}

// ---- per-i tap table: 5 pair-patterns (pre-shifted packed bf16) + silu + si.
struct Tab {
  unsigned Dm1, D0, D1, D2, D3;  // pair patterns for lower-slot rel -1..3
  unsigned SG;                   // silu bf16 (low 16)
  int si;                        // floor((xn+1)*17) in [0,33]
};

__device__ __forceinline__ Tab mktab(float xv) {
  float xn = fminf(fmaxf(xv, -0.99f), 0.99f);
  float u = (xn + 1.0f) * 17.0f;                  // 1/h = 17
  float sf = floorf(u);
  int si = (int)sf;
  float f = u - sf, g = 1.0f - f;
  float f2 = f * f, g2 = g * g;
  float t0 = g2 * g * (1.f / 6.f);
  float t1 = 0.66666667f - f2 + 0.5f * f2 * f;
  float t2 = 0.66666667f - g2 + 0.5f * g2 * g;
  float t3 = f2 * f * (1.f / 6.f);
  if (si == 0) t0 = 0.f;     // tap at grid c=-1 doesn't exist
  if (si == 33) t3 = 0.f;    // tap at c=35 is the silu slot, never a spline tap
  float sg = xn / (1.0f + __expf(-xn));
  unsigned P01 = (unsigned)f2bf(t0) | ((unsigned)f2bf(t1) << 16);
  unsigned P23 = (unsigned)f2bf(t2) | ((unsigned)f2bf(t3) << 16);
  Tab t;
  t.Dm1 = P01 << 16;                       // (0,    tap0)
  t.D0 = P01;                              // (tap0, tap1)
  t.D1 = (P01 >> 16) | (P23 << 16);        // (tap1, tap2)
  t.D2 = P23;                              // (tap2, tap3)
  t.D3 = P23 >> 16;                        // (tap3, 0)
  t.SG = (unsigned)f2bf(sg);
  t.si = si;
  return t;
}

// ---- fused GEMM: A-tile generated in-kernel, W staged from W2 image. ----
// R5/R8 geometry: 256x256 tile, 8 waves, triple-buffered, counted vmcnt,
// baked chunk-XOR swizzle on both A (ds_write side) and W (memory image).
__global__ __launch_bounds__(512) void kan_gemm6(const float* __restrict__ x,
                                                 const unsigned short* __restrict__ W2,
                                                 float* __restrict__ out) {
  __shared__ __align__(16) unsigned short As[3][BM * BK];   // 3 x 16 KB
  __shared__ __align__(16) unsigned short Ws[3][BN * BK];   // 3 x 16 KB

  const int tid = threadIdx.x;
  const int mt = blockIdx.x, nt = blockIdx.y, kc = blockIdx.z;

  const int lane = tid & 63;
  const int wid = tid >> 6;                      // 0..7
  const int wm = (wid & 3) * 64;                 // 4 m-wave rows
  const int wn = (wid >> 2) * 128;               // 2 n-wave cols
  const int lm = lane & 15;
  const int quad = lane >> 4;
  const int koS = (quad ^ ((lm >> 1) & 3)) * 8;  // swizzled chunk address

  // A-builder role: thread covers row r, slots [16h, 16h+16).
  const int r = tid & 255;
  const int h = tid >> 8;                        // wave-uniform (waves 0-3 / 4-7)
  const int hbase = h * 16;
  const int swzA = (r >> 1) & 3;
  const int posA = (2 * h) ^ swzA;               // image position of chunk 2h
  const int posB = (2 * h + 1) ^ swzA;
  const float* xrow = x + (size_t)(mt * BM + r) * IN_DIM;

  f32x4 acc[4][8];
#pragma unroll
  for (int a = 0; a < 4; ++a)
#pragma unroll
    for (int b = 0; b < 8; ++b) acc[a][b] = f32x4{0.f, 0.f, 0.f, 0.f};

  // W staging: wave wid owns 16-row chunks g = 2*wid, 2*wid+1 (1KB each).
  const unsigned short* Wbase = W2 + (size_t)(nt * BN) * 32 + lane * 8;
  auto issueW = [&](int buf, int w) {
    const size_t woff = (size_t)w * (OUT_DIM * 32);
#pragma unroll
    for (int c = 0; c < 2; ++c) {
      const int g = wid * 2 + c;
      __builtin_amdgcn_global_load_lds(
          (const __attribute__((address_space(1))) unsigned int*)(Wbase + woff + (size_t)g * 512),
          (__attribute__((address_space(3))) unsigned int*)(&Ws[buf][g * 512]),
          16, 0, 0);
    }
  };

  // uniform K-state: kc*WPC*32 = kc*9216 is a multiple of 36 -> c0 = 0.
  int i0 = (kc * WPC * 32) / KPI;
  int c0 = kc * WPC * 32 - i0 * KPI;

  // per-lane tap tables for i0, i0+1; xN prefetched for i0+2.
  float xc = xrow[i0];
  float xd = xrow[(i0 + 1 < IN_DIM) ? i0 + 1 : IN_DIM - 1];
  float xN = xrow[(i0 + 2 < IN_DIM) ? i0 + 2 : IN_DIM - 1];
  Tab T0 = mktab(xc);
  Tab T1 = mktab(xd);

  // assemble window (uniform c0) into As[buf]: 8 slot-pairs via 5-pattern
  // select. seg0 FIRST (R10 fix): seg1 pairs have tl0 >= 4 so no shadowing;
  // the only seg0/seg1 selector collision (c=34 pair, si1==0 -> tl1==-1)
  // then fires only when the lower slot is truly zero, and T1.Dm1|si1=0
  // is (0,0). Silu fix-up last (c=35 belongs to segment i0 -> T0.SG).
  auto assembleA = [&](int buf) {
    const int J0 = hbase + c0 + 1 - T0.si;       // lower-slot rel for seg0
    const int J1 = hbase + c0 - 35 - T1.si;      // lower-slot rel for seg1
    const int sl = 35 - c0 - hbase;              // silu local slot (uniform)
    unsigned pr[8];
#pragma unroll
    for (int p = 0; p < 8; ++p) {
      const int tl0 = J0 + 2 * p;
      const int tl1 = J1 + 2 * p;
      unsigned v = (tl0 == -1) ? T0.Dm1
                 : (tl0 == 0)  ? T0.D0
                 : (tl0 == 1)  ? T0.D1
                 : (tl0 == 2)  ? T0.D2
                 : (tl0 == 3)  ? T0.D3
                 : (tl1 == -1) ? T1.Dm1
                 : (tl1 == 0)  ? T1.D0
                 : (tl1 == 1)  ? T1.D1
                 : (tl1 == 2)  ? T1.D2
                 : (tl1 == 3)  ? T1.D3
                 : 0u;
      if (sl == 2 * p)     v = (v & 0xFFFF0000u) | T0.SG;
      if (sl == 2 * p + 1) v = (v & 0x0000FFFFu) | (T0.SG << 16);
      pr[p] = v;
    }
    *(uint4*)(&As[buf][r * BK + posA * 8]) = make_uint4(pr[0], pr[1], pr[2], pr[3]);
    *(uint4*)(&As[buf][r * BK + posB * 8]) = make_uint4(pr[4], pr[5], pr[6], pr[7]);
  };

  // prologue: window w0 into buf 0.
  assembleA(0);
  issueW(0, kc * WPC);

  int cur = 0, nxt = 1;
  for (int step = 0; step < WPC; ++step) {
    if (step + 1 < WPC) {
      // advance uniform state to window step+1; rotate tables.
      int c0n = c0 + 32;
      const bool rot = (c0n >= KPI);             // wave-uniform
      if (rot) {
        c0 = c0n - KPI;
        ++i0;
        T0 = T1;
        T1 = mktab(xN);
        xN = xrow[(i0 + 2 < IN_DIM) ? i0 + 2 : IN_DIM - 1];
      } else {
        c0 = c0n;
      }
      issueW(nxt, kc * WPC + step + 1);
      assembleA(nxt);
      // Drain exactly the prev step's 2 W loads. Rotation steps carry the
      // xN prefetch as an extra outstanding VMEM op -> vmcnt(3); otherwise
      // vmcnt(2). Either way this step's 2 W loads stay in flight and we
      // never wait on a just-issued load.
      if (rot)
        asm volatile("s_waitcnt vmcnt(3) lgkmcnt(0)\ns_barrier" ::: "memory");
      else
        asm volatile("s_waitcnt vmcnt(2) lgkmcnt(0)\ns_barrier" ::: "memory");
    } else {
      asm volatile("s_waitcnt vmcnt(0) lgkmcnt(0)\ns_barrier" ::: "memory");
    }

    uint4 af[4];
#pragma unroll
    for (int mi = 0; mi < 4; ++mi)
      af[mi] = *(const uint4*)(&As[cur][(wm + mi * 16 + lm) * BK + koS]);
#pragma unroll
    for (int hh = 0; hh < 2; ++hh) {
      uint4 bfr[4];
#pragma unroll
      for (int nj = 0; nj < 4; ++nj)
        bfr[nj] = *(const uint4*)(&Ws[cur][(wn + hh * 64 + nj * 16 + lm) * BK + koS]);
#pragma unroll
      for (int mi = 0; mi < 4; ++mi)
#pragma unroll
        for (int nj = 0; nj < 4; ++nj)
          acc[mi][hh * 4 + nj] = __builtin_amdgcn_mfma_f32_16x16x32_bf16(
              __builtin_bit_cast(bf16x8, af[mi]), __builtin_bit_cast(bf16x8, bfr[nj]),
              acc[mi][hh * 4 + nj], 0, 0, 0);
    }

    cur = nxt;
    nxt = (nxt == 2) ? 0 : nxt + 1;
  }

  // epilogue: C/D layout col=lane&15 (n), row=quad*4+reg (m); split-K atomics
#pragma unroll
  for (int mi = 0; mi < 4; ++mi)
#pragma unroll
    for (int ni = 0; ni < 8; ++ni)
#pragma unroll
      for (int rr = 0; rr < 4; ++rr) {
        int row = mt * BM + wm + mi * 16 + quad * 4 + rr;
        int col = nt * BN + wn + ni * 16 + lm;
        atomicAdd(&out[(size_t)row * OUT_DIM + col], acc[mi][ni][rr]);
      }
}

// ================= fallback path (R1-proven), used only if ws too small ====
#define FB_BM 128
#define FB_BN 128
#define FB_BKPA 40
#define FB_KCH 9216
#define FB_NSTEP 288

template <bool USE_WB>
__global__ __launch_bounds__(256) void kan_gemm_fb(const float* __restrict__ x,
                                                   const unsigned short* __restrict__ wb,
                                                   const float* __restrict__ sw,
                                                   const float* __restrict__ bs,
                                                   float* __restrict__ out) {
  __shared__ __align__(16) unsigned short As[FB_BM * FB_BKPA];
  __shared__ __align__(16) unsigned short Wsm[FB_BN * FB_BKPA];

  const int tid = threadIdx.x;
  const int mt = blockIdx.x, nt = blockIdx.y, kc = blockIdx.z;
  const int sb = tid & 127;
  const int shalf = tid >> 7;
  const int klo = shalf * 16;
  const int wrow = tid >> 1;
  const int whal = tid & 1;
  const int lane = tid & 63;
  const int wid = tid >> 6;
  const int wm = (wid & 1) * 64;
  const int wn = (wid >> 1) * 64;
  const int lm = lane & 15;
  const int quad = lane >> 4;
  const int ko = quad * 8;

  f32x4 acc[4][4];
#pragma unroll
  for (int a = 0; a < 4; ++a)
#pragma unroll
    for (int b = 0; b < 4; ++b) acc[a][b] = f32x4{0.f, 0.f, 0.f, 0.f};

  const float* xrow = x + (size_t)(mt * FB_BM + sb) * IN_DIM;

  for (int step = 0; step < FB_NSTEP; ++step) {
    const int kbase = kc * FB_KCH + step * BK;
    {
      uint4 z = make_uint4(0, 0, 0, 0);
      uint4* az = (uint4*)(&As[sb * FB_BKPA + klo]);
      az[0] = z;
      az[1] = z;
    }
    {
      const int ilo = kbase / KPI;
      const int ihi = (kbase + BK - 1) / KPI;
      for (int ii = ilo; ii <= ihi; ++ii) {
        float xv = xrow[ii];
        float xn = fminf(fmaxf(xv, -0.99f), 0.99f);
        float u = (xn + 1.0f) * 17.0f;
        float sf = floorf(u);
        int s = (int)sf;
        float f = u - sf, g = 1.0f - f;
        float f2 = f * f, g2 = g * g;
        float v0 = g2 * g * (1.f / 6.f);
        float v1 = 0.66666667f - f2 + 0.5f * f2 * f;
        float v2 = 0.66666667f - g2 + 0.5f * g2 * g;
        float v3 = f2 * f * (1.f / 6.f);
        float sig = xn / (1.0f + __expf(-xn));
        const int kb0 = ii * KPI - kbase;
#pragma unroll
        for (int t = 0; t < 4; ++t) {
          int c = s - 1 + t;
          float v = (t == 0) ? v0 : (t == 1) ? v1 : (t == 2) ? v2 : v3;
          int kq = kb0 + c;
          if (c >= 0 && c < NC && kq >= klo && kq < klo + 16)
            As[sb * FB_BKPA + kq] = f2bf(v);
        }
        int kqb = kb0 + NC;
        if (kqb >= klo && kqb < klo + 16) As[sb * FB_BKPA + kqb] = f2bf(sig);
      }
    }
    {
      const int j = nt * FB_BN + wrow;
      unsigned int p[8];
#pragma unroll
      for (int q = 0; q < 8; ++q) {
        unsigned int lohi = 0;
#pragma unroll
        for (int hh = 0; hh < 2; ++hh) {
          int k = kbase + whal * 16 + q * 2 + hh;
          int i = k / KPI;
          int c = k - i * KPI;
          float v = (c < NC) ? sw[(size_t)i * (OUT_DIM * NC) + (size_t)j * NC + c]
                             : bs[(size_t)i * OUT_DIM + j];
          lohi |= ((unsigned int)f2bf(v)) << (16 * hh);
        }
        p[q] = lohi;
      }
      uint4* wd = (uint4*)(&Wsm[wrow * FB_BKPA + whal * 16]);
      wd[0] = make_uint4(p[0], p[1], p[2], p[3]);
      wd[1] = make_uint4(p[4], p[5], p[6], p[7]);
    }

    __syncthreads();

    uint4 af[4], bfr[4];
#pragma unroll
    for (int mi = 0; mi < 4; ++mi)
      af[mi] = *(const uint4*)(&As[(wm + mi * 16 + lm) * FB_BKPA + ko]);
#pragma unroll
    for (int ni = 0; ni < 4; ++ni)
      bfr[ni] = *(const uint4*)(&Wsm[(wn + ni * 16 + lm) * FB_BKPA + ko]);
#pragma unroll
    for (int mi = 0; mi < 4; ++mi)
#pragma unroll
      for (int ni = 0; ni < 4; ++ni)
        acc[mi][ni] = __builtin_amdgcn_mfma_f32_16x16x32_bf16(
            __builtin_bit_cast(bf16x8, af[mi]), __builtin_bit_cast(bf16x8, bfr[ni]),
            acc[mi][ni], 0, 0, 0);

    __syncthreads();
  }

#pragma unroll
  for (int mi = 0; mi < 4; ++mi)
#pragma unroll
    for (int ni = 0; ni < 4; ++ni)
#pragma unroll
      for (int rr = 0; rr < 4; ++rr) {
        int row = mt * FB_BM + wm + mi * 16 + quad * 4 + rr;
        int col = nt * FB_BN + wn + ni * 16 + lm;
        atomicAdd(&out[(size_t)row * OUT_DIM + col], acc[mi][ni][rr]);
      }
}

extern "C" void kernel_launch(void* const* d_in, const int* in_sizes, int n_in,
                              void* d_out, int out_size, void* d_ws, size_t ws_size,
                              hipStream_t stream) {
  const float* x = (const float*)d_in[0];
  const float* sw = (const float*)d_in[1];
  const float* bs = (const float*)d_in[2];
  float* out = (float*)d_out;

  hipMemsetAsync(d_out, 0, (size_t)MROWS * OUT_DIM * sizeof(float), stream);

  const size_t WB_BYTES = (size_t)NW * OUT_DIM * 32 * sizeof(unsigned short);  // 75.5 MB

  if (ws_size >= WB_BYTES) {
    unsigned short* w2 = (unsigned short*)d_ws;
    prep_w2<<<dim3(NW, OUT_DIM / 256), 256, 0, stream>>>(sw, bs, w2);
    kan_gemm6<<<dim3(MROWS / BM, OUT_DIM / BN, NSPLIT), 512, 0, stream>>>(x, w2, out);
  } else {
    kan_gemm_fb<false><<<dim3(32, 8, 4), 256, 0, stream>>>(x, nullptr, sw, bs, out);
  }
}

// Round 7
// 714.264 us; speedup vs baseline: 1.7150x; 1.7150x over previous
//
#include <hip/hip_runtime.h>
#include <hip/hip_bf16.h>

// FastKANLayer as one bf16 MFMA GEMM: out[b,j] = A[b,k] @ Wb[k,j], k = i*36+c.
//   c<35: A = cubic B-spline basis (4-tap sparse), Wb = spline_weight[i,j,c]
//   c==35: A = silu(clip(x)),                      Wb = base_scale[i,j]
// M=4096, N=1024, K=36864.
// R12 = R11 resubmitted verbatim (R11 died to container infra, same as R7;
// R8's identical-resubmit precedent ran clean. prep_w2s re-audited: slab-0
// read ends exactly at sw's last element for the worst block, slab-1
// guarded + clamped, LDS 71.7KB, block-uniform branches only).
// R11: revert to the R8-verified staged pipeline (gemm5 337us, a2t ~120us)
// and fix the newly-isolated hotspot: prep_w2 was 245us (R10 residual
// measurement) because of 32 scalar 140B-strided gather loads per thread.
// prep_w2s stages the two sw slabs into LDS with dense coalesced float4
// loads (35840B contiguous per slab) and reads slots at LDS stride 35
// floats (35 = 3 mod 32, coprime -> conflict-free). Slab-1 load skipped
// when the window doesn't cross an i-boundary (1/9 of blocks).
// R10 lesson: fused A-generation is VALU-floor-bound (~292us issue alone,
// phase-serialized with MFMA at 2 waves/SIMD) -- staged A2 wins.
// Carried verbatim: kan_gemm5 (R8: 337us, MfmaUtil 39%, conflicts 0),
// prep_a2t (R8), NSPLIT=4 atomics, baked chunk-XOR swizzle.

#define IN_DIM 1024
#define OUT_DIM 1024
#define NC 35
#define KPI 36
#define KTOT (IN_DIM * KPI)      // 36864
#define NW (KTOT / 32)           // 1152 k-windows of 32
#define MROWS 4096
#define BM 256
#define BN 256
#define BK 32
#define NSPLIT 4
#define WPC (NW / NSPLIT)        // 288 windows per kc chunk

typedef __attribute__((ext_vector_type(8))) __bf16 bf16x8;
typedef __attribute__((ext_vector_type(4))) float f32x4;

__device__ __forceinline__ unsigned short f2bf(float f) {
  unsigned int u = __builtin_bit_cast(unsigned int, f);
  u = (u + 0x7FFFu + ((u >> 16) & 1u)) >> 16;   // RNE
  return (unsigned short)u;
}

__device__ __forceinline__ uint4 pack8(const unsigned short* v) {
  uint4 t4;
  t4.x = (unsigned)v[0] | ((unsigned)v[1] << 16);
  t4.y = (unsigned)v[2] | ((unsigned)v[3] << 16);
  t4.z = (unsigned)v[4] | ((unsigned)v[5] << 16);
  t4.w = (unsigned)v[6] | ((unsigned)v[7] << 16);
  return t4;
}

// ---- prep: W2[w][n][32] bf16 (75.5 MB), swizzled LDS tile image. ----
// R11 rewrite: LDS slab transpose. Slab q = sw[iq][n0:n0+256][0:35]
// (35840 B contiguous) loaded as dense float4 (fully coalesced); slot
// reads from LDS at stride 35 floats (coprime with 32 banks).
__global__ __launch_bounds__(256) void prep_w2s(const float* __restrict__ sw,
                                                const float* __restrict__ bs,
                                                unsigned short* __restrict__ w2) {
  __shared__ __align__(16) float sbuf[2][256 * NC];   // 2 x 35.0 KB
  const int tid = threadIdx.x;
  const int w = blockIdx.x;
  const int n0 = blockIdx.y * 256;
  const int k0 = w * 32;
  const int i0 = k0 / KPI;
  const int off0 = k0 - i0 * KPI;                 // in {0,4,...,32}
  const int split = (KPI - off0 < 32) ? (KPI - off0) : 32;
  const int i1 = (i0 + 1 < IN_DIM) ? (i0 + 1) : i0;

  {  // dense coalesced slab loads: 2240 float4 per slab, 256 threads.
    const float4* s0 = (const float4*)(sw + ((size_t)i0 * OUT_DIM + n0) * NC);
    float4* d0 = (float4*)(&sbuf[0][0]);
    for (int t = tid; t < 256 * NC / 4; t += 256) d0[t] = s0[t];
    if (split < 32) {                             // slab 1 actually used
      const float4* s1 = (const float4*)(sw + ((size_t)i1 * OUT_DIM + n0) * NC);
      float4* d1 = (float4*)(&sbuf[1][0]);
      for (int t = tid; t < 256 * NC / 4; t += 256) d1[t] = s1[t];
    }
  }
  const float bsv = bs[(size_t)i0 * OUT_DIM + n0 + tid];
  __syncthreads();

  const int swz = (tid >> 1) & 3;                 // row bits 1:2 -> chunk XOR
  unsigned short v[32];
#pragma unroll
  for (int kk = 0; kk < 32; ++kk) {
    const int c = off0 + kk;                      // block-uniform
    float fv;
    if (kk < split)                               // uniform branch
      fv = (c < NC) ? sbuf[0][tid * NC + c] : bsv;   // c==NC -> silu weight
    else
      fv = sbuf[1][tid * NC + (kk - split)];      // c' = kk-split <= 27 < NC
    v[kk] = f2bf(fv);
  }
  uint4* dst = (uint4*)(w2 + ((size_t)w * OUT_DIM + n0 + tid) * 32);
#pragma unroll
  for (int j = 0; j < 4; ++j) dst[j ^ swz] = pack8(&v[8 * j]);
}

// ---- prep: A2[w][b][32] bf16 basis (302 MB), swizzled LDS tile image. ----
// (R8-verified, unchanged.) Block = (k-group g: i in [8g,8g+8), w in
// [9g,9g+9)) x (256-row b-slab). x read row-wise float4; slot->(i,c)
// compile-time; bf16 conversion once per i.
__global__ __launch_bounds__(256) void prep_a2t(const float* __restrict__ x,
                                                unsigned short* __restrict__ a2) {
  const int tid = threadIdx.x;
  const int g = blockIdx.x;                       // 0..127
  const int b = blockIdx.y * 256 + tid;
  const int i0 = g * 8;
  const int w0 = g * 9;
  const int swz = (tid >> 1) & 3;

  float4 xa = *(const float4*)(x + (size_t)b * IN_DIM + i0);
  float4 xb = *(const float4*)(x + (size_t)b * IN_DIM + i0 + 4);
  const float xv[8] = {xa.x, xa.y, xa.z, xa.w, xb.x, xb.y, xb.z, xb.w};

  int si[8];
  unsigned short tb0[8], tb1[8], tb2[8], tb3[8], sgb[8];
#pragma unroll
  for (int q = 0; q < 8; ++q) {
    float xn = fminf(fmaxf(xv[q], -0.99f), 0.99f);
    float u = (xn + 1.0f) * 17.0f;                // 1/h = 17
    float sf = floorf(u);
    si[q] = (int)sf;
    float f = u - sf, gg = 1.0f - f;
    float f2 = f * f, g2 = gg * gg;
    tb0[q] = f2bf(g2 * gg * (1.f / 6.f));
    tb1[q] = f2bf(0.66666667f - f2 + 0.5f * f2 * f);
    tb2[q] = f2bf(0.66666667f - g2 + 0.5f * g2 * gg);
    tb3[q] = f2bf(f2 * f * (1.f / 6.f));
    sgb[q] = f2bf(xn / (1.0f + __expf(-xn)));
  }

#pragma unroll
  for (int wl = 0; wl < 9; ++wl) {
    unsigned short v[32];
#pragma unroll
    for (int kk = 0; kk < 32; ++kk) {
      const int kr = wl * 32 + kk;                // compile-time
      const int q = kr / KPI;                     // compile-time i-index
      const int c = kr % KPI;                     // compile-time coeff
      unsigned short val;
      if (c == NC) {
        val = sgb[q];
      } else {
        int rel = c - (si[q] - 1);
        val = (rel == 0) ? tb0[q]
            : (rel == 1) ? tb1[q]
            : (rel == 2) ? tb2[q]
            : (rel == 3) ? tb3[q] : (unsigned short)0;
      }
      v[kk] = val;
    }
    uint4* dst = (uint4*)(a2 + ((size_t)(w0 + wl) * MROWS + b) * 32);
#pragma unroll
    for (int j = 0; j < 4; ++j) dst[j ^ swz] = pack8(&v[8 * j]);
  }
}

// ---- fast GEMM (R8-verified, unchanged): 256x256, 8 waves, triple-
// buffered async K-loop, counted vmcnt(4), baked-swizzle ds_reads. ----
__global__ __launch_bounds__(512) void kan_gemm5(const unsigned short* __restrict__ A2,
                                                 const unsigned short* __restrict__ W2,
                                                 float* __restrict__ out) {
  __shared__ __align__(16) unsigned short As[3][BM * BK];   // 3 x 16 KB
  __shared__ __align__(16) unsigned short Ws[3][BN * BK];   // 3 x 16 KB

  const int tid = threadIdx.x;
  const int mt = blockIdx.x, nt = blockIdx.y, kc = blockIdx.z;

  const int lane = tid & 63;
  const int wid = tid >> 6;                      // 0..7
  const int wm = (wid & 3) * 64;                 // 4 m-wave rows
  const int wn = (wid >> 2) * 128;               // 2 n-wave cols
  const int lm = lane & 15;
  const int quad = lane >> 4;
  const int koS = (quad ^ ((lm >> 1) & 3)) * 8;  // swizzled chunk address

  f32x4 acc[4][8];
#pragma unroll
  for (int a = 0; a < 4; ++a)
#pragma unroll
    for (int b = 0; b < 8; ++b) acc[a][b] = f32x4{0.f, 0.f, 0.f, 0.f};

  // staging: wave wid owns 16-row chunks g = 2*wid, 2*wid+1 of both tiles.
  // Each global_load_lds: contiguous 1KB (16 rows x 32 k), lane*16B.
  const unsigned short* Abase = A2 + (size_t)(mt * BM) * 32 + lane * 8;
  const unsigned short* Wbase = W2 + (size_t)(nt * BN) * 32 + lane * 8;

  auto issue = [&](int buf, int w) {
    const size_t aoff = (size_t)w * (MROWS * 32);
    const size_t woff = (size_t)w * (OUT_DIM * 32);
#pragma unroll
    for (int c = 0; c < 2; ++c) {
      const int g = wid * 2 + c;
      __builtin_amdgcn_global_load_lds(
          (const __attribute__((address_space(1))) unsigned int*)(Abase + aoff + (size_t)g * 512),
          (__attribute__((address_space(3))) unsigned int*)(&As[buf][g * 512]),
          16, 0, 0);
      __builtin_amdgcn_global_load_lds(
          (const __attribute__((address_space(1))) unsigned int*)(Wbase + woff + (size_t)g * 512),
          (__attribute__((address_space(3))) unsigned int*)(&Ws[buf][g * 512]),
          16, 0, 0);
    }
  };

  issue(0, kc * WPC);
  int cur = 0, nxt = 1;
  for (int step = 0; step < WPC; ++step) {
    if (step + 1 < WPC) {
      issue(nxt, kc * WPC + step + 1);
      // wait this step's 4 loads only; prefetch (newest 4) stays in flight
      asm volatile("s_waitcnt vmcnt(4) lgkmcnt(0)\ns_barrier" ::: "memory");
    } else {
      asm volatile("s_waitcnt vmcnt(0) lgkmcnt(0)\ns_barrier" ::: "memory");
    }

    uint4 af[4];
#pragma unroll
    for (int mi = 0; mi < 4; ++mi)
      af[mi] = *(const uint4*)(&As[cur][(wm + mi * 16 + lm) * BK + koS]);
#pragma unroll
    for (int h = 0; h < 2; ++h) {
      uint4 bfr[4];
#pragma unroll
      for (int nj = 0; nj < 4; ++nj)
        bfr[nj] = *(const uint4*)(&Ws[cur][(wn + h * 64 + nj * 16 + lm) * BK + koS]);
#pragma unroll
      for (int mi = 0; mi < 4; ++mi)
#pragma unroll
        for (int nj = 0; nj < 4; ++nj)
          acc[mi][h * 4 + nj] = __builtin_amdgcn_mfma_f32_16x16x32_bf16(
              __builtin_bit_cast(bf16x8, af[mi]), __builtin_bit_cast(bf16x8, bfr[nj]),
              acc[mi][h * 4 + nj], 0, 0, 0);
    }

    cur = nxt;
    nxt = (nxt == 2) ? 0 : nxt + 1;
  }

  // epilogue: C/D layout col=lane&15 (n), row=quad*4+reg (m); split-K atomics
#pragma unroll
  for (int mi = 0; mi < 4; ++mi)
#pragma unroll
    for (int ni = 0; ni < 8; ++ni)
#pragma unroll
      for (int r = 0; r < 4; ++r) {
        int row = mt * BM + wm + mi * 16 + quad * 4 + r;
        int col = nt * BN + wn + ni * 16 + lm;
        atomicAdd(&out[(size_t)row * OUT_DIM + col], acc[mi][ni][r]);
      }
}

// ================= fallback path (R1-proven), used only if ws too small ====
#define FB_BM 128
#define FB_BN 128
#define FB_BKPA 40
#define FB_KCH 9216
#define FB_NSTEP 288

template <bool USE_WB>
__global__ __launch_bounds__(256) void kan_gemm_fb(const float* __restrict__ x,
                                                   const unsigned short* __restrict__ wb,
                                                   const float* __restrict__ sw,
                                                   const float* __restrict__ bs,
                                                   float* __restrict__ out) {
  __shared__ __align__(16) unsigned short As[FB_BM * FB_BKPA];
  __shared__ __align__(16) unsigned short Wsm[FB_BN * FB_BKPA];

  const int tid = threadIdx.x;
  const int mt = blockIdx.x, nt = blockIdx.y, kc = blockIdx.z;
  const int sb = tid & 127;
  const int shalf = tid >> 7;
  const int klo = shalf * 16;
  const int wrow = tid >> 1;
  const int whal = tid & 1;
  const int lane = tid & 63;
  const int wid = tid >> 6;
  const int wm = (wid & 1) * 64;
  const int wn = (wid >> 1) * 64;
  const int lm = lane & 15;
  const int quad = lane >> 4;
  const int ko = quad * 8;

  f32x4 acc[4][4];
#pragma unroll
  for (int a = 0; a < 4; ++a)
#pragma unroll
    for (int b = 0; b < 4; ++b) acc[a][b] = f32x4{0.f, 0.f, 0.f, 0.f};

  const float* xrow = x + (size_t)(mt * FB_BM + sb) * IN_DIM;

  for (int step = 0; step < FB_NSTEP; ++step) {
    const int kbase = kc * FB_KCH + step * BK;
    {
      uint4 z = make_uint4(0, 0, 0, 0);
      uint4* az = (uint4*)(&As[sb * FB_BKPA + klo]);
      az[0] = z;
      az[1] = z;
    }
    {
      const int ilo = kbase / KPI;
      const int ihi = (kbase + BK - 1) / KPI;
      for (int ii = ilo; ii <= ihi; ++ii) {
        float xv = xrow[ii];
        float xn = fminf(fmaxf(xv, -0.99f), 0.99f);
        float u = (xn + 1.0f) * 17.0f;
        float sf = floorf(u);
        int s = (int)sf;
        float f = u - sf, g = 1.0f - f;
        float f2 = f * f, g2 = g * g;
        float v0 = g2 * g * (1.f / 6.f);
        float v1 = 0.66666667f - f2 + 0.5f * f2 * f;
        float v2 = 0.66666667f - g2 + 0.5f * g2 * g;
        float v3 = f2 * f * (1.f / 6.f);
        float sig = xn / (1.0f + __expf(-xn));
        const int kb0 = ii * KPI - kbase;
#pragma unroll
        for (int t = 0; t < 4; ++t) {
          int c = s - 1 + t;
          float v = (t == 0) ? v0 : (t == 1) ? v1 : (t == 2) ? v2 : v3;
          int kq = kb0 + c;
          if (c >= 0 && c < NC && kq >= klo && kq < klo + 16)
            As[sb * FB_BKPA + kq] = f2bf(v);
        }
        int kqb = kb0 + NC;
        if (kqb >= klo && kqb < klo + 16) As[sb * FB_BKPA + kqb] = f2bf(sig);
      }
    }
    {
      const int j = nt * FB_BN + wrow;
      unsigned int p[8];
#pragma unroll
      for (int q = 0; q < 8; ++q) {
        unsigned int lohi = 0;
#pragma unroll
        for (int hh = 0; hh < 2; ++hh) {
          int k = kbase + whal * 16 + q * 2 + hh;
          int i = k / KPI;
          int c = k - i * KPI;
          float v = (c < NC) ? sw[(size_t)i * (OUT_DIM * NC) + (size_t)j * NC + c]
                             : bs[(size_t)i * OUT_DIM + j];
          lohi |= ((unsigned int)f2bf(v)) << (16 * hh);
        }
        p[q] = lohi;
      }
      uint4* wd = (uint4*)(&Wsm[wrow * FB_BKPA + whal * 16]);
      wd[0] = make_uint4(p[0], p[1], p[2], p[3]);
      wd[1] = make_uint4(p[4], p[5], p[6], p[7]);
    }

    __syncthreads();

    uint4 af[4], bfr[4];
#pragma unroll
    for (int mi = 0; mi < 4; ++mi)
      af[mi] = *(const uint4*)(&As[(wm + mi * 16 + lm) * FB_BKPA + ko]);
#pragma unroll
    for (int ni = 0; ni < 4; ++ni)
      bfr[ni] = *(const uint4*)(&Wsm[(wn + ni * 16 + lm) * FB_BKPA + ko]);
#pragma unroll
    for (int mi = 0; mi < 4; ++mi)
#pragma unroll
      for (int ni = 0; ni < 4; ++ni)
        acc[mi][ni] = __builtin_amdgcn_mfma_f32_16x16x32_bf16(
            __builtin_bit_cast(bf16x8, af[mi]), __builtin_bit_cast(bf16x8, bfr[ni]),
            acc[mi][ni], 0, 0, 0);

    __syncthreads();
  }

#pragma unroll
  for (int mi = 0; mi < 4; ++mi)
#pragma unroll
    for (int ni = 0; ni < 4; ++ni)
#pragma unroll
      for (int r = 0; r < 4; ++r) {
        int row = mt * FB_BM + wm + mi * 16 + quad * 4 + r;
        int col = nt * FB_BN + wn + ni * 16 + lm;
        atomicAdd(&out[(size_t)row * OUT_DIM + col], acc[mi][ni][r]);
      }
}

extern "C" void kernel_launch(void* const* d_in, const int* in_sizes, int n_in,
                              void* d_out, int out_size, void* d_ws, size_t ws_size,
                              hipStream_t stream) {
  const float* x = (const float*)d_in[0];
  const float* sw = (const float*)d_in[1];
  const float* bs = (const float*)d_in[2];
  float* out = (float*)d_out;

  hipMemsetAsync(d_out, 0, (size_t)MROWS * OUT_DIM * sizeof(float), stream);

  const size_t WB_BYTES = (size_t)NW * OUT_DIM * 32 * sizeof(unsigned short);  // 75.5 MB
  const size_t A_BYTES = (size_t)NW * MROWS * 32 * sizeof(unsigned short);     // 302 MB

  if (ws_size >= WB_BYTES + A_BYTES) {
    unsigned short* w2 = (unsigned short*)d_ws;
    unsigned short* a2 = (unsigned short*)((char*)d_ws + WB_BYTES);
    prep_w2s<<<dim3(NW, OUT_DIM / 256), 256, 0, stream>>>(sw, bs, w2);
    prep_a2t<<<dim3(KTOT / 288, MROWS / 256), 256, 0, stream>>>(x, a2);
    kan_gemm5<<<dim3(MROWS / BM, OUT_DIM / BN, NSPLIT), 512, 0, stream>>>(a2, w2, out);
  } else {
    kan_gemm_fb<false><<<dim3(32, 8, 4), 256, 0, stream>>>(x, nullptr, sw, bs, out);
  }
}